// Round 10
// baseline (383.035 us; speedup 1.0000x reference)
//
#include <hip/hip_runtime.h>
#include <cstddef>

#define H 128
#define W 128
#define P_THRESH 20

typedef float f4u __attribute__((ext_vector_type(4), aligned(4)));
typedef int   i4u __attribute__((ext_vector_type(4), aligned(4)));
typedef float nf2 __attribute__((ext_vector_type(2)));

// r9 structure, 2x work per thread: block = 8 rows x 128 cols, thread = 2x2 px.
//   Masks: 10 rows (r0-1..r0+8) packed ONCE per block into LDS (border writes
//   folded: byte = dir if prob<=20 AND target in-image, else 8). Guard word +
//   per-row pad => edge-case-free window extraction (2 LDS words + funnel
//   shift, sh in {8,24}).
//   Input: 4 unaligned f4u row-loads per thread feed BOTH output rows
//   (halo via load window; L1 absorbs the overlap); 6 cndmask/row edge fix.
//   Per-px instruction count drops ~25% vs r9 (shared loads/extraction/sums,
//   halved per-wave setup); mask HBM amp 1.5x -> 1.25x.
__global__ __launch_bounds__(256, 8)
void brown_kernel(const float* __restrict__ inp,
                  const int*  __restrict__ dirp,
                  const int*  __restrict__ prb,
                  float* __restrict__ out)
{
    // [0] = guard; rows lr=0..9 at [1+33*lr+w], w=32 is the 4B pad (all 8s)
    __shared__ unsigned int s_mk[331];   // 1324 B

    const int tid   = threadIdx.x;
    const int bid   = blockIdx.x;
    const int slice = bid >> 4;
    const int r0    = (bid & 15) << 3;   // 8 rows per block
    const size_t base = (size_t)slice * (size_t)(H * W);

    const int lane = tid & 63;
    const int wid  = tid >> 6;           // wave 0..3
    const int pr   = r0 + (wid << 1);    // top output row of this thread
    const int j0   = lane << 1;          // own cols j0, j0+1

    // ---- input loads first (independent of LDS, fly across the barrier) ----
    const int cl  = (lane == 0) ? 0 : ((lane == 63) ? (W - 4) : (j0 - 1));
    const int gA  = (pr == 0) ? 1 : (pr - 1);         // reflect row -1 -> 1
    const int gD  = (pr == H - 2) ? (H - 2) : (pr + 2); // reflect row 128 -> 126
    const float* ip = inp + base;
    const f4u iA = *(const f4u*)(ip + (size_t)gA * W + cl);
    const f4u iB = *(const f4u*)(ip + (size_t)pr * W + cl);
    const f4u iC = *(const f4u*)(ip + (size_t)(pr + 1) * W + cl);
    const f4u iD = *(const f4u*)(ip + (size_t)gD * W + cl);

    // ---- pack phase: 10 mask rows x 32 words, once per block ----
    #pragma unroll
    for (int it = 0; it < 2; ++it) {
        const int idx = it * 256 + tid;
        if (idx < 320) {
            const int lr = idx >> 5;     // LDS mask row 0..9
            const int w  = idx & 31;     // word = 4 cols
            const int gr = r0 + lr - 1;  // image row
            unsigned m;
            if ((unsigned)gr < (unsigned)H) {
                const i4u dv = *(const i4u*)(dirp + base + (size_t)gr * W + 4 * w);
                const i4u pv = *(const i4u*)(prb  + base + (size_t)gr * W + 4 * w);
                const unsigned a = (pv.x <= P_THRESH) ? (unsigned)dv.x : 8u;
                const unsigned b = (pv.y <= P_THRESH) ? (unsigned)dv.y : 8u;
                const unsigned c = (pv.z <= P_THRESH) ? (unsigned)dv.z : 8u;
                const unsigned e = (pv.w <= P_THRESH) ? (unsigned)dv.w : 8u;
                m = a | (b << 8) | (c << 16) | (e << 24);
                if (gr == 0) {              // top row: d in {0,1,2} writes up -> OOB
                    unsigned mm = 0;
                    #pragma unroll
                    for (int i2 = 0; i2 < 4; ++i2) {
                        unsigned bb = (m >> (8 * i2)) & 255u;
                        bb = (bb <= 2u) ? 8u : bb;
                        mm |= bb << (8 * i2);
                    }
                    m = mm;
                } else if (gr == H - 1) {   // bottom row: d in {6,7} writes down -> OOB
                    unsigned mm = 0;
                    #pragma unroll
                    for (int i2 = 0; i2 < 4; ++i2) {
                        unsigned bb = (m >> (8 * i2)) & 255u;
                        bb = (bb >= 6u) ? 8u : bb;
                        mm |= bb << (8 * i2);
                    }
                    m = mm;
                }
                if (w == 0) {               // image col 0: d in {0,3,6} (dj=-1) -> OOB
                    const unsigned b0 = m & 255u;
                    if ((0x49u >> b0) & 1u) m = (m & ~255u) | 8u;
                }
                if (w == 31) {              // image col 127: d in {2,5} (dj=+1) -> OOB
                    const unsigned b3 = m >> 24;
                    if ((0x24u >> b3) & 1u) m = (m & 0x00FFFFFFu) | (8u << 24);
                }
            } else {
                m = 0x08080808u;            // out-of-image rows never source writes
            }
            s_mk[1 + 33 * lr + w] = m;
            if (w == 31) s_mk[1 + 33 * lr + 32] = 0x08080808u;   // row pad
        }
    }
    if (tid == 0) s_mk[0] = 0x08080808u;    // guard before row 0
    __syncthreads();

    // ---- mask windows for 4 rows lr = 2*wid .. 2*wid+3 (edge-case-free) ----
    // byte addr of col j0-1 (incl. guard) = 4 + 132*lr + j0 - 1 = 132*lr + j0 + 3
    unsigned mr[4];
    #pragma unroll
    for (int dr = 0; dr < 4; ++dr) {
        const int lr   = (wid << 1) + dr;
        const int addr = 132 * lr + (j0 + 3);
        const unsigned w0 = s_mk[addr >> 2];
        const unsigned w1 = s_mk[(addr >> 2) + 1];
        const int sh = 8 * (addr & 3);       // lane even: 24, odd: 8 (never 0)
        mr[dr] = (w0 >> sh) | (w1 << (32 - sh));
    }

    // ---- float windows: cols {j0-1, j0, j0+1, j0+2}; 6 cndmask/row edge fix ----
    const bool e0 = (lane == 0), e63 = (lane == 63), eE = e0 | e63;
    auto fixrow = [&](f4u i, float v[4]) {
        // lane 0 loaded {0..3}, wants {1,0,1,2}; lane 63 loaded {124..127},
        // wants {125,126,127,126}; others exact.
        v[0] = eE ? i.y : i.x;
        v[1] = e0 ? i.x : (e63 ? i.z : i.y);
        v[2] = e0 ? i.y : (e63 ? i.w : i.z);
        v[3] = eE ? i.z : i.w;
    };
    float v0[4], v1[4], v2[4], v3[4];
    fixrow(iA, v0); fixrow(iB, v1); fixrow(iC, v2); fixrow(iD, v3);

    // ---- column sums (s12 shared by both output rows) ----
    float s12[4], csT[4], csB[4];
    #pragma unroll
    for (int w = 0; w < 4; ++w) {
        s12[w] = v1[w] + v2[w];
        csT[w] = v0[w] + s12[w];
        csB[w] = s12[w] + v3[w];
    }

    // ---- cascade for one output row (2 px) ----
    auto crow = [&](unsigned mT, unsigned mM, unsigned mB,
                    const float vT[4], const float vM[4], const float vBo[4],
                    const float cs[4]) -> nf2 {
        nf2 res;
        #pragma unroll
        for (int p = 0; p < 2; ++p) {
            const float avg = (cs[p] + cs[p + 1] + cs[p + 2]) * (1.0f / 9.0f);
            const unsigned wT = mT >> (8 * p);   // b0=m[p] b1=m[p+1] b2=m[p+2]
            const unsigned wM = mM >> (8 * p);
            const unsigned wB = mB >> (8 * p);

            float val = vM[p + 1];   // input[i][j]
            int dl = -1;             // direction of last A-write
            // A-writes ascending d; source offset = (-di,-dj)
            if (((wB >> 16) & 255u) == 0u) { val = vBo[p + 2]; dl = 0; }
            if (((wB >>  8) & 255u) == 1u) { val = vBo[p + 1]; dl = 1; }
            if (( wB        & 255u) == 2u) { val = vBo[p];     dl = 2; }
            if (((wM >> 16) & 255u) == 3u) { val = vM[p + 2];  dl = 3; }
            if (( wM        & 255u) == 5u) { val = vM[p];      dl = 5; }
            if (((wT >> 16) & 255u) == 6u) { val = vT[p + 2];  dl = 6; }
            if (((wT >>  8) & 255u) == 7u) { val = vT[p + 1];  dl = 7; }

            // B-write (avg): borders pre-folded -> just active + priority
            const int msel = (int)((wM >> 8) & 255u);
            if ((msel < 8) & (msel >= dl)) val = avg;
            res[p] = val;
        }
        return res;
    };

    const nf2 resT = crow(mr[0], mr[1], mr[2], v0, v1, v2, csT);
    const nf2 resB = crow(mr[1], mr[2], mr[3], v1, v2, v3, csB);
    *(nf2*)(out + base + (size_t)pr * W + j0)       = resT;
    *(nf2*)(out + base + (size_t)(pr + 1) * W + j0) = resB;
}

extern "C" void kernel_launch(void* const* d_in, const int* in_sizes, int n_in,
                              void* d_out, int out_size, void* d_ws, size_t ws_size,
                              hipStream_t stream) {
    const float* inp  = (const float*)d_in[0];
    const int*   dirp = (const int*)d_in[1];
    const int*   prb  = (const int*)d_in[2];
    float* out = (float*)d_out;

    const int slices = in_sizes[0] / (H * W);   // 2048
    const int grid = slices * 16;               // 8 rows per block -> 32768
    brown_kernel<<<grid, 256, 0, stream>>>(inp, dirp, prb, out);
}